// Round 8
// baseline (347.365 us; speedup 1.0000x reference)
//
#include <hip/hip_runtime.h>

// Xonv2D: location-dependent 3x3 conv.
//   x:       (B=4, CIN=16, H=128, W=128)  fp32   -- 4 MB, L2-hot
//   weights: (H, W, COUT=16, CIN=16, 3, 3) fp32  -- 151 MB, read-once stream
//   bias:    (H, W, COUT) fp32
//   out:     (B, COUT, H, W) fp32
//
// V13: zero-LDS max-occupancy probe -- the last untested axis.
//  Falsification table (V5-V12): weight supply pinned 1.7-1.9 TB/s across
//  staging (DMA/reg/NT), occupancy 8-16 w/CU, lines/site 400 vs 92, wait
//  discipline, cross-CU address order, pipeline depth 1 vs 2. The one
//  configuration never run: >16 waves/CU. All prior versions carried
//  33-72KB LDS (transpose buffers / x slabs), capping residency. V12's
//  direct-fragment map removes the need for LDS entirely:
//    lane l := (o = l>>2, g = l&3)  =>  fragment = f4 [9l, 9l+9)
//  9 consecutive dwordx4 straight into FMA-input registers. x consumed by
//  per-lane loads: within each load instruction the 16 lanes sharing g read
//  the SAME address -> coalesces to 4 distinct addresses, and x is L2-hot
//  (4MB). So: no LDS, no barrier, no transpose, one site per wave, exit.
//  ~70 VGPR + __launch_bounds__(256,6) -> 24 waves/CU (1.5x best so far);
//  wave churn keeps 9KB bursts issuing continuously: ~200KB+ outstanding
//  per CU vs <=147KB in all prior versions.
//  Pre-committed read: kernel <=65us -> outstanding-bytes was binding,
//  iterate on occupancy. Flat 84-92 -> occupancy axis complete (8/12/16/24
//  all equal), declare empirical ceiling: 151MB / 1.8TB/s = 84us kernel
//  + ~140us timed harness re-poison = the observed ~225us total.
//
// Kept: XCD banding (row-aligned), wave-uniform border path, butterfly
// reduce over c-groups (xor 1, xor 2 under the direct map), single store
// per lane (lane (o,g) keeps batch b=g), bias dword load.

#define HWD   128
#define CIND  16
#define COUTD 16

typedef float f4  __attribute__((ext_vector_type(4)));
typedef float f4u __attribute__((ext_vector_type(4), aligned(4)));

__global__ __launch_bounds__(256, 6) void xonv2d_kernel(
    const float* __restrict__ x,
    const float* __restrict__ wts,
    const float* __restrict__ bias,
    float* __restrict__ out)
{
    const int lane = threadIdx.x & 63;
    const int wave = threadIdx.x >> 6;

    // XCD banding: XCD k = blockIdx%8 handles sites [k*2048, (k+1)*2048).
    const int xcd  = blockIdx.x & 7;
    const int idx  = blockIdx.x >> 3;
    const int site = xcd * 2048 + idx * 4 + wave;   // 0 .. 16383
    const int h = site >> 7;
    const int w = site & 127;

    const int o  = lane >> 2;    // output channel (direct-fragment map)
    const int g  = lane & 3;     // channel group: c in [4g, 4g+4)
    const int c0 = g * 4;

    // ---- direct fragment: 9 consecutive dwordx4, straight to registers.
    //      Issued first: the long-latency HBM stream ramps immediately. ----
    const f4* gwl = (const f4*)wts + (size_t)site * 576 + 9 * lane;
    f4 wv[9];
    #pragma unroll
    for (int j = 0; j < 9; ++j) wv[j] = gwl[j];
    const float* wf = (const float*)wv;

    // bias: one dword (L2-hot), issued while the weight burst is in flight
    const float bv = bias[(size_t)site * COUTD + o];

    float acc[4] = {0.f, 0.f, 0.f, 0.f};

    // w <= 125: f4 row loads read cols w-1..w+2 <= 127, always in-bounds.
    const bool interior = (h >= 1) & (h <= HWD - 2) & (w >= 1) & (w <= HWD - 3);

    if (interior) {
        #pragma unroll
        for (int cc = 0; cc < 4; ++cc) {
            #pragma unroll
            for (int b = 0; b < 4; ++b) {
                // 16 lanes sharing g read identical addresses: each load
                // instruction coalesces to 4 distinct (g) addresses, L2-hot.
                const float* xb = x + (((size_t)(b * CIND + c0 + cc) * HWD + (h - 1)) * HWD) + (w - 1);
                f4 r0 = *(const f4u*)(xb);
                f4 r1 = *(const f4u*)(xb + HWD);
                f4 r2 = *(const f4u*)(xb + 2 * HWD);
                const float* wr = wf + cc * 9;
                acc[b] = fmaf(r0.x, wr[0], acc[b]);
                acc[b] = fmaf(r0.y, wr[1], acc[b]);
                acc[b] = fmaf(r0.z, wr[2], acc[b]);
                acc[b] = fmaf(r1.x, wr[3], acc[b]);
                acc[b] = fmaf(r1.y, wr[4], acc[b]);
                acc[b] = fmaf(r1.z, wr[5], acc[b]);
                acc[b] = fmaf(r2.x, wr[6], acc[b]);
                acc[b] = fmaf(r2.y, wr[7], acc[b]);
                acc[b] = fmaf(r2.z, wr[8], acc[b]);
            }
        }
    } else {
        #pragma unroll
        for (int cc = 0; cc < 4; ++cc) {
            #pragma unroll
            for (int b = 0; b < 4; ++b) {
                const float* xb = x + ((size_t)(b * CIND + c0 + cc)) * (HWD * HWD);
                #pragma unroll
                for (int kh = 0; kh < 3; ++kh) {
                    const int hy = h + kh - 1;
                    #pragma unroll
                    for (int kw = 0; kw < 3; ++kw) {
                        const int wx = w + kw - 1;
                        const bool ok = (hy >= 0) & (hy < HWD) & (wx >= 0) & (wx < HWD);
                        const float xv = ok ? xb[hy * HWD + wx] : 0.f;
                        acc[b] = fmaf(xv, wf[cc * 9 + kh * 3 + kw], acc[b]);
                    }
                }
            }
        }
    }

    // ---- butterfly reduce over the 4 c-groups (lane bits 0,1) ----
    float r[4];
    #pragma unroll
    for (int b = 0; b < 4; ++b) {
        float v = acc[b];
        v += __shfl_xor(v, 1);
        v += __shfl_xor(v, 2);
        r[b] = v;
    }

    // lane (o,g) stores batch b = g: one store, all 64 lanes active
    const float vout = (g == 0) ? r[0] : (g == 1) ? r[1] : (g == 2) ? r[2] : r[3];
    out[((size_t)(g * COUTD + o)) * (HWD * HWD) + h * HWD + w] = vout + bv;
}

extern "C" void kernel_launch(void* const* d_in, const int* in_sizes, int n_in,
                              void* d_out, int out_size, void* d_ws, size_t ws_size,
                              hipStream_t stream) {
    const float* x    = (const float*)d_in[0];
    const float* wts  = (const float*)d_in[1];
    const float* bias = (const float*)d_in[2];
    float* out = (float*)d_out;

    // 16384 sites, 4 waves (= 4 sites) per 256-thread block, zero LDS.
    // __launch_bounds__(256,6): VGPR cap ~85 -> 6 blocks/CU = 24 waves/CU.
    const int blocks = (HWD * HWD) / 4;
    xonv2d_kernel<<<blocks, 256, 0, stream>>>(x, wts, bias, out);
}